// Round 7
// baseline (274.090 us; speedup 1.0000x reference)
//
#include <hip/hip_runtime.h>

// TimeTempTransformerModule: MLP(1->16->32) -> biGRU(H=32, SEQ=32) -> meanpool -> dec(64->128)
// B = 32768 rows, fp32 in/out.
//
// v6 = v5 (swapped-operand MFMA recurrence, zero-LDS step loop) with the two
// GRU directions SPLIT ACROSS TWO WAVES of a 128-thread block:
//   wave0 = forward, wave1 = backward, same 16 batch rows.
//   -> 4096 waves total = 4 waves/SIMD (v5 was wave-count-bound at 2/SIMD,
//      VALUBusy 62% from dependency stalls).
//   Pooled results exchanged via 4KB LDS; each wave does half the decoder.
// Numerics identical to v5: g^T = W @ h^T, D-layout==B-layout under k-perm
// pi(q,e), 3-term hi/lo split for gh, biases in dead k>=16 slots.

#define SEQB 32
#define NH   16
#define DH   32

typedef __attribute__((ext_vector_type(4))) float f32x4;
typedef __attribute__((ext_vector_type(8))) short s16x8;
typedef __attribute__((ext_vector_type(4))) unsigned int u32x4;

#define MFMA_B16(a, b, c) __builtin_amdgcn_mfma_f32_16x16x32_bf16((a), (b), (c), 0, 0, 0)

// ws layout (bytes)
#define OFF_AHI  0u        // [dir][t<6][lane<64] 16B  gh weights hi (trunc)
#define OFF_ALO  12288u    // [dir][t<6][lane] 16B     gh weights lo (rne resid)
#define OFF_AGX  24576u    // [dir][t<6][lane] 16B     gx weights (rne) + bias slots
#define OFF_ADEC 36864u    // [kc<2][t<8][lane] 16B    decoder weights (rne)
#define OFF_WC   53248u    // [dir][96][16] f32 temp
#define OFF_BC   65536u    // [dir][96] f32 temp

__device__ __forceinline__ unsigned short bf16_rne(float x) {
    unsigned u = __float_as_uint(x);
    return (unsigned short)((u + 0x7fffu + ((u >> 16) & 1u)) >> 16);
}
// (a & 0xffff0000) | (b >> 16)  -- packs bf16(b) into lo16, bf16(a) into hi16 (trunc)
__device__ __forceinline__ unsigned pack_hi(unsigned a, unsigned b) {
    return __builtin_amdgcn_perm(a, b, 0x07060302u);
}
__device__ __forceinline__ int kperm(int q, int e) {  // pi(q,e)
    return (e < 4) ? (4 * q + e) : (4 * q + 12 + e);
}

__global__ __launch_bounds__(1024) void gru_precompute_kernel(
    const float* __restrict__ w_ih_f, const float* __restrict__ b_ih_f,
    const float* __restrict__ w_ih_b, const float* __restrict__ b_ih_b,
    const float* __restrict__ w2, const float* __restrict__ b2,
    const float* __restrict__ whh_f, const float* __restrict__ whh_b,
    const float* __restrict__ bhh_f, const float* __restrict__ bhh_b,
    const float* __restrict__ w_dec,
    unsigned char* __restrict__ ws)
{
    const int t = threadIdx.x;
    float* WC = (float*)(ws + OFF_WC);
    float* BC = (float*)(ws + OFF_BC);

    if (t < 192) {  // Wc = w_ih@w2 [96x16], bc = w_ih@b2 + b_ih
        const int dir = t / 96, g = t % 96;
        const float* wih = dir ? w_ih_b : w_ih_f;
        const float* bih = dir ? b_ih_b : b_ih_f;
        float acc[NH];
#pragma unroll
        for (int m = 0; m < NH; ++m) acc[m] = 0.0f;
        float ab = bih[g];
        for (int d = 0; d < DH; ++d) {
            float wv = wih[g * DH + d];
            ab = fmaf(wv, b2[d], ab);
#pragma unroll
            for (int m = 0; m < NH; ++m) acc[m] = fmaf(wv, w2[d * NH + m], acc[m]);
        }
#pragma unroll
        for (int m = 0; m < NH; ++m) WC[(dir * 96 + g) * NH + m] = acc[m];
        BC[dir * 96 + g] = ab;
    }
    __syncthreads();

    if (t < 768) {  // gh A-frags (hi/lo, k-permuted) + gx A-frags (rne + bias slots)
        const int dir = t / 384, r = t % 384, tt = r / 64, l = r % 64;
        const int gate = tt * 16 + (l & 15);
        const int q = l >> 4;
        const float* whh = dir ? whh_b : whh_f;
        const float* bhh = dir ? bhh_b : bhh_f;
        unsigned short h8[8], l8[8], g8[8];
#pragma unroll
        for (int e = 0; e < 8; ++e) {
            const int u = kperm(q, e);
            float w = whh[gate * DH + u];
            unsigned ub = __float_as_uint(w);
            h8[e] = (unsigned short)(ub >> 16);
            l8[e] = bf16_rne(w - __uint_as_float(ub & 0xffff0000u));
            float gxv = (e < 4) ? WC[(dir * 96 + gate) * NH + 4 * q + e] : 0.0f;
            g8[e] = bf16_rne(gxv);
        }
        // bias slots: (q=0,e=4) hi, (q=1,e=4) lo; pairs with constant 1.0 in B
        const float bias = BC[dir * 96 + gate] + ((gate < 64) ? bhh[gate] : 0.0f);
        const unsigned bb = __float_as_uint(bias);
        if (q == 0) g8[4] = (unsigned short)(bb >> 16);
        if (q == 1) g8[4] = bf16_rne(bias - __uint_as_float(bb & 0xffff0000u));

        unsigned short* dh = (unsigned short*)(ws + OFF_AHI + dir * 6144u + tt * 1024u + l * 16u);
        unsigned short* dl = (unsigned short*)(ws + OFF_ALO + dir * 6144u + tt * 1024u + l * 16u);
        unsigned short* dg = (unsigned short*)(ws + OFF_AGX + dir * 6144u + tt * 1024u + l * 16u);
#pragma unroll
        for (int e = 0; e < 8; ++e) { dh[e] = h8[e]; dl[e] = l8[e]; dg[e] = g8[e]; }
    }
    {  // decoder A-frags: A[out][k] k-permuted, k = pi(q,e) + 32*kc
        const int kc = t / 512, r = t % 512, tt = r / 64, l = r % 64;
        const int outn = tt * 16 + (l & 15);
        const int q = l >> 4;
        unsigned short* dd = (unsigned short*)(ws + OFF_ADEC + kc * 8192u + tt * 1024u + l * 16u);
#pragma unroll
        for (int e = 0; e < 8; ++e)
            dd[e] = bf16_rne(w_dec[outn * 64 + kperm(q, e) + 32 * kc]);
    }
}

__global__ __launch_bounds__(128, 4) void gru_mfma_kernel(
    const float* __restrict__ x,
    const float* __restrict__ w1, const float* __restrict__ b1,
    const float* __restrict__ bhh_f, const float* __restrict__ bhh_b,
    const unsigned char* __restrict__ ws,
    const float* __restrict__ b_dec,
    float* __restrict__ out)
{
    __shared__ __align__(16) u32x4 lds_comb[2][64][2];  // [wave][lane][hi/lo] 4KB

    const int tid = threadIdx.x;
    const int dir = tid >> 6;   // wave0 = fwd, wave1 = bwd
    const int l   = tid & 63;
    const int n = l & 15;       // batch row (D col / B col)
    const int q = l >> 4;       // k-quad / D row-quad
    const int rowbase = blockIdx.x * 16;
    const float* xr = x + (size_t)(rowbase + n) * SEQB;

    const float4 w1q = *(const float4*)(w1 + 4 * q);  // h1 units 4q..4q+3
    const float4 b1q = *(const float4*)(b1 + 4 * q);

    const float* bhh = dir ? bhh_b : bhh_f;
    const unsigned char* pAhi = ws + OFF_AHI + dir * 6144u + l * 16u;
    const unsigned char* pAlo = ws + OFF_ALO + dir * 6144u + l * 16u;
    const unsigned char* pAgx = ws + OFF_AGX + dir * 6144u + l * 16u;
    s16x8 Ahi[6], Alo[6], Agx[6];
#pragma unroll
    for (int tt = 0; tt < 6; ++tt) {
        Ahi[tt] = *(const s16x8*)(pAhi + tt * 1024);
        Alo[tt] = *(const s16x8*)(pAlo + tt * 1024);
        Agx[tt] = *(const s16x8*)(pAgx + tt * 1024);
    }
#pragma unroll
    for (int tt = 0; tt < 6; ++tt)
        asm volatile("" : "+v"(Ahi[tt]), "+v"(Alo[tt]), "+v"(Agx[tt]));
    // n-gate gh bias (C-init of the gh chain): gates 64+4q+rg (tile4), 80+4q+rg (tile5)
    const float4 bn0f = *(const float4*)(bhh + 64 + 4 * q);
    const float4 bn1f = *(const float4*)(bhh + 80 + 4 * q);
    const f32x4 bhn0 = {bn0f.x, bn0f.y, bn0f.z, bn0f.w};
    const f32x4 bhn1 = {bn1f.x, bn1f.y, bn1f.z, bn1f.w};

    float hL[4] = {0, 0, 0, 0}, hH[4] = {0, 0, 0, 0};
    float pL[4] = {0, 0, 0, 0}, pH[4] = {0, 0, 0, 0};

#pragma unroll 1
    for (int blk = 0; blk < 4; ++blk) {
        const int bb = dir ? 3 - blk : blk;
        const float4 xa = *(const float4*)(xr + bb * 8);
        const float4 xb = *(const float4*)(xr + bb * 8 + 4);
        float xs[8] = {xa.x, xa.y, xa.z, xa.w, xb.x, xb.y, xb.z, xb.w};
        if (dir) {  // wave-uniform branch: reverse within the 8-step chunk
            float r0 = xs[0], r1 = xs[1], r2 = xs[2], r3 = xs[3];
            xs[0] = xs[7]; xs[1] = xs[6]; xs[2] = xs[5]; xs[3] = xs[4];
            xs[4] = r3; xs[5] = r2; xs[6] = r1; xs[7] = r0;
        }

#pragma unroll
        for (int i = 0; i < 8; ++i) {
            // ---- B_h1 frag: h1[row n][4q+e] e<4 (in-lane), e4=1.0 (bias), e5..7=0
            float t0 = fmaf(xs[i], w1q.x, b1q.x); t0 = fmaxf(t0, 0.01f * t0);
            float t1 = fmaf(xs[i], w1q.y, b1q.y); t1 = fmaxf(t1, 0.01f * t1);
            float t2 = fmaf(xs[i], w1q.z, b1q.z); t2 = fmaxf(t2, 0.01f * t2);
            float t3 = fmaf(xs[i], w1q.w, b1q.w); t3 = fmaxf(t3, 0.01f * t3);
            u32x4 ub1;
            ub1.x = pack_hi(__float_as_uint(t1), __float_as_uint(t0));
            ub1.y = pack_hi(__float_as_uint(t3), __float_as_uint(t2));
            ub1.z = 0x00003F80u;  // e4 = 1.0 (bias partner), e5 = 0
            ub1.w = 0u;           // e6, e7 = 0
            const s16x8 Bh1 = __builtin_bit_cast(s16x8, ub1);

            // ---- B_h frags hi/lo from in-lane h state (u-order: L=4q+rg, H=16+4q+rg)
            unsigned uL0 = __float_as_uint(hL[0]), uL1 = __float_as_uint(hL[1]);
            unsigned uL2 = __float_as_uint(hL[2]), uL3 = __float_as_uint(hL[3]);
            unsigned uH0 = __float_as_uint(hH[0]), uH1 = __float_as_uint(hH[1]);
            unsigned uH2 = __float_as_uint(hH[2]), uH3 = __float_as_uint(hH[3]);
            u32x4 phh;
            phh.x = pack_hi(uL1, uL0); phh.y = pack_hi(uL3, uL2);
            phh.z = pack_hi(uH1, uH0); phh.w = pack_hi(uH3, uH2);
            float lL0 = hL[0] - __uint_as_float(uL0 & 0xffff0000u);
            float lL1 = hL[1] - __uint_as_float(uL1 & 0xffff0000u);
            float lL2 = hL[2] - __uint_as_float(uL2 & 0xffff0000u);
            float lL3 = hL[3] - __uint_as_float(uL3 & 0xffff0000u);
            float lH0 = hH[0] - __uint_as_float(uH0 & 0xffff0000u);
            float lH1 = hH[1] - __uint_as_float(uH1 & 0xffff0000u);
            float lH2 = hH[2] - __uint_as_float(uH2 & 0xffff0000u);
            float lH3 = hH[3] - __uint_as_float(uH3 & 0xffff0000u);
            u32x4 phl;
            phl.x = pack_hi(__float_as_uint(lL1), __float_as_uint(lL0));
            phl.y = pack_hi(__float_as_uint(lL3), __float_as_uint(lL2));
            phl.z = pack_hi(__float_as_uint(lH1), __float_as_uint(lH0));
            phl.w = pack_hi(__float_as_uint(lH3), __float_as_uint(lH2));
            const s16x8 Bhhi = __builtin_bit_cast(s16x8, phh);
            const s16x8 Bhlo = __builtin_bit_cast(s16x8, phl);

            const f32x4 z4 = {0.0f, 0.0f, 0.0f, 0.0f};
            // r tiles (gates 0..15 / 16..31): gx+bias then 3-term gh, one chain
            f32x4 a0 = MFMA_B16(Agx[0], Bh1, z4);
            a0 = MFMA_B16(Alo[0], Bhhi, a0); a0 = MFMA_B16(Ahi[0], Bhlo, a0); a0 = MFMA_B16(Ahi[0], Bhhi, a0);
            f32x4 a1 = MFMA_B16(Agx[1], Bh1, z4);
            a1 = MFMA_B16(Alo[1], Bhhi, a1); a1 = MFMA_B16(Ahi[1], Bhlo, a1); a1 = MFMA_B16(Ahi[1], Bhhi, a1);
            // z tiles
            f32x4 a2 = MFMA_B16(Agx[2], Bh1, z4);
            a2 = MFMA_B16(Alo[2], Bhhi, a2); a2 = MFMA_B16(Ahi[2], Bhlo, a2); a2 = MFMA_B16(Ahi[2], Bhhi, a2);
            f32x4 a3 = MFMA_B16(Agx[3], Bh1, z4);
            a3 = MFMA_B16(Alo[3], Bhhi, a3); a3 = MFMA_B16(Ahi[3], Bhlo, a3); a3 = MFMA_B16(Ahi[3], Bhhi, a3);
            // n tiles: gx (with bcn in bias slot) and gh (C-init = bhn) kept separate
            f32x4 x4a = MFMA_B16(Agx[4], Bh1, z4);
            f32x4 x5a = MFMA_B16(Agx[5], Bh1, z4);
            f32x4 g4 = MFMA_B16(Alo[4], Bhhi, bhn0);
            g4 = MFMA_B16(Ahi[4], Bhlo, g4); g4 = MFMA_B16(Ahi[4], Bhhi, g4);
            f32x4 g5 = MFMA_B16(Alo[5], Bhhi, bhn1);
            g5 = MFMA_B16(Ahi[5], Bhlo, g5); g5 = MFMA_B16(Ahi[5], Bhhi, g5);

            // ---- activations + state update (all in-lane, fp32)
#pragma unroll
            for (int rg = 0; rg < 4; ++rg) {
                float rL = __builtin_amdgcn_rcpf(1.0f + __expf(-a0[rg]));
                float zL = __builtin_amdgcn_rcpf(1.0f + __expf(-a2[rg]));
                float tL = fmaf(rL, g4[rg], x4a[rg]);
                float nL = fmaf(-2.0f, __builtin_amdgcn_rcpf(1.0f + __expf(tL + tL)), 1.0f);
                hL[rg] = fmaf(zL, hL[rg] - nL, nL);
                pL[rg] += hL[rg];

                float rH = __builtin_amdgcn_rcpf(1.0f + __expf(-a1[rg]));
                float zH = __builtin_amdgcn_rcpf(1.0f + __expf(-a3[rg]));
                float tH = fmaf(rH, g5[rg], x5a[rg]);
                float nH = fmaf(-2.0f, __builtin_amdgcn_rcpf(1.0f + __expf(tH + tH)), 1.0f);
                hH[rg] = fmaf(zH, hH[rg] - nH, nH);
                pH[rg] += hH[rg];
            }
        }
    }

    // ---- pack this wave's pooled into bf16 hi/lo frags, exchange via LDS ----
    {
#pragma unroll
        for (int rg = 0; rg < 4; ++rg) { pL[rg] *= 0.03125f; pH[rg] *= 0.03125f; }
        unsigned v0, v1, v2, v3;
        u32x4 ph, pl;
        v0 = __float_as_uint(pL[0]); v1 = __float_as_uint(pL[1]);
        v2 = __float_as_uint(pL[2]); v3 = __float_as_uint(pL[3]);
        ph.x = pack_hi(v1, v0); ph.y = pack_hi(v3, v2);
        pl.x = pack_hi(__float_as_uint(pL[1] - __uint_as_float(v1 & 0xffff0000u)),
                       __float_as_uint(pL[0] - __uint_as_float(v0 & 0xffff0000u)));
        pl.y = pack_hi(__float_as_uint(pL[3] - __uint_as_float(v3 & 0xffff0000u)),
                       __float_as_uint(pL[2] - __uint_as_float(v2 & 0xffff0000u)));
        v0 = __float_as_uint(pH[0]); v1 = __float_as_uint(pH[1]);
        v2 = __float_as_uint(pH[2]); v3 = __float_as_uint(pH[3]);
        ph.z = pack_hi(v1, v0); ph.w = pack_hi(v3, v2);
        pl.z = pack_hi(__float_as_uint(pH[1] - __uint_as_float(v1 & 0xffff0000u)),
                       __float_as_uint(pH[0] - __uint_as_float(v0 & 0xffff0000u)));
        pl.w = pack_hi(__float_as_uint(pH[3] - __uint_as_float(v3 & 0xffff0000u)),
                       __float_as_uint(pH[2] - __uint_as_float(v2 & 0xffff0000u)));

        lds_comb[dir][l][0] = ph;
        lds_comb[dir][l][1] = pl;
        __syncthreads();
        const u32x4 oh = lds_comb[dir ^ 1][l][0];
        const u32x4 ol = lds_comb[dir ^ 1][l][1];

        s16x8 BFh, BFl, BBh, BBl;
        if (dir == 0) {
            BFh = __builtin_bit_cast(s16x8, ph); BFl = __builtin_bit_cast(s16x8, pl);
            BBh = __builtin_bit_cast(s16x8, oh); BBl = __builtin_bit_cast(s16x8, ol);
        } else {
            BFh = __builtin_bit_cast(s16x8, oh); BFl = __builtin_bit_cast(s16x8, ol);
            BBh = __builtin_bit_cast(s16x8, ph); BBl = __builtin_bit_cast(s16x8, pl);
        }

        // ---- decoder: this wave handles output tiles tt = dir*4 .. dir*4+3
#pragma unroll
        for (int ti = 0; ti < 4; ++ti) {
            const int tt = dir * 4 + ti;
            const s16x8 A0 = *(const s16x8*)(ws + OFF_ADEC + tt * 1024u + l * 16u);
            const s16x8 A1 = *(const s16x8*)(ws + OFF_ADEC + 8192u + tt * 1024u + l * 16u);
            const float4 bd = *(const float4*)(b_dec + tt * 16 + 4 * q);
            f32x4 acc = {bd.x, bd.y, bd.z, bd.w};
            acc = MFMA_B16(A0, BFl, acc);
            acc = MFMA_B16(A1, BBl, acc);
            acc = MFMA_B16(A0, BFh, acc);
            acc = MFMA_B16(A1, BBh, acc);
            *(float4*)(out + (size_t)(rowbase + n) * 128 + tt * 16 + 4 * q) =
                make_float4(acc[0], acc[1], acc[2], acc[3]);
        }
    }
}

extern "C" void kernel_launch(void* const* d_in, const int* in_sizes, int n_in,
                              void* d_out, int out_size, void* d_ws, size_t ws_size,
                              hipStream_t stream)
{
    const float* x    = (const float*)d_in[0];
    const float* w1   = (const float*)d_in[1];
    const float* b1   = (const float*)d_in[2];
    const float* w2   = (const float*)d_in[3];
    const float* b2   = (const float*)d_in[4];
    const float* wihf = (const float*)d_in[5];
    const float* whhf = (const float*)d_in[6];
    const float* bihf = (const float*)d_in[7];
    const float* bhhf = (const float*)d_in[8];
    const float* wihb = (const float*)d_in[9];
    const float* whhb = (const float*)d_in[10];
    const float* bihb = (const float*)d_in[11];
    const float* bhhb = (const float*)d_in[12];
    const float* wdec = (const float*)d_in[13];
    const float* bdec = (const float*)d_in[14];
    float* out = (float*)d_out;
    unsigned char* ws = (unsigned char*)d_ws;

    const int B = in_sizes[0] / SEQB;  // 32768
    const int grid = B / 16;           // 16 rows per 128-thread (2-wave) block

    hipLaunchKernelGGL(gru_precompute_kernel, dim3(1), dim3(1024), 0, stream,
                       wihf, bihf, wihb, bihb, w2, b2, whhf, whhb, bhhf, bhhb, wdec, ws);
    hipLaunchKernelGGL(gru_mfma_kernel, dim3(grid), dim3(128), 0, stream,
                       x, w1, b1, bhhf, bhhb, ws, bdec, out);
}

// Round 8
// 85.698 us; speedup vs baseline: 3.1983x; 3.1983x over previous
//
#include <hip/hip_runtime.h>

// TimeTempTransformerModule: MLP(1->16->32) -> biGRU(H=32, SEQ=32) -> meanpool -> dec(64->128)
// B = 32768 rows, fp32 in/out.
//
// v7 = v6 (two directions split across two waves of a 128-thread block) with
// __launch_bounds__(128, 2) instead of (128, 4): the (128,4) bound drove the
// register allocator to a 64-VGPR budget -> all 18 weight frags spilled to
// scratch (FETCH_SIZE 2.4MB -> 688MB, dur 83 -> 274us). At (128,2) the wave's
// natural ~112 VGPRs fit under every cap interpretation, and <=128 VGPR still
// permits the 4 waves/SIMD the 2-wave-block split was built to reach.
// Numerics identical to v5/v6: g^T = W @ h^T swapped-operand MFMA recurrence,
// D-layout==B-layout under k-perm pi(q,e), 3-term hi/lo split for gh,
// biases in dead k>=16 slots, zero LDS in the step loop.

#define SEQB 32
#define NH   16
#define DH   32

typedef __attribute__((ext_vector_type(4))) float f32x4;
typedef __attribute__((ext_vector_type(8))) short s16x8;
typedef __attribute__((ext_vector_type(4))) unsigned int u32x4;

#define MFMA_B16(a, b, c) __builtin_amdgcn_mfma_f32_16x16x32_bf16((a), (b), (c), 0, 0, 0)

// ws layout (bytes)
#define OFF_AHI  0u        // [dir][t<6][lane<64] 16B  gh weights hi (trunc)
#define OFF_ALO  12288u    // [dir][t<6][lane] 16B     gh weights lo (rne resid)
#define OFF_AGX  24576u    // [dir][t<6][lane] 16B     gx weights (rne) + bias slots
#define OFF_ADEC 36864u    // [kc<2][t<8][lane] 16B    decoder weights (rne)
#define OFF_WC   53248u    // [dir][96][16] f32 temp
#define OFF_BC   65536u    // [dir][96] f32 temp

__device__ __forceinline__ unsigned short bf16_rne(float x) {
    unsigned u = __float_as_uint(x);
    return (unsigned short)((u + 0x7fffu + ((u >> 16) & 1u)) >> 16);
}
// (a & 0xffff0000) | (b >> 16)  -- packs bf16(b) into lo16, bf16(a) into hi16 (trunc)
__device__ __forceinline__ unsigned pack_hi(unsigned a, unsigned b) {
    return __builtin_amdgcn_perm(a, b, 0x07060302u);
}
__device__ __forceinline__ int kperm(int q, int e) {  // pi(q,e)
    return (e < 4) ? (4 * q + e) : (4 * q + 12 + e);
}

__global__ __launch_bounds__(1024) void gru_precompute_kernel(
    const float* __restrict__ w_ih_f, const float* __restrict__ b_ih_f,
    const float* __restrict__ w_ih_b, const float* __restrict__ b_ih_b,
    const float* __restrict__ w2, const float* __restrict__ b2,
    const float* __restrict__ whh_f, const float* __restrict__ whh_b,
    const float* __restrict__ bhh_f, const float* __restrict__ bhh_b,
    const float* __restrict__ w_dec,
    unsigned char* __restrict__ ws)
{
    const int t = threadIdx.x;
    float* WC = (float*)(ws + OFF_WC);
    float* BC = (float*)(ws + OFF_BC);

    if (t < 192) {  // Wc = w_ih@w2 [96x16], bc = w_ih@b2 + b_ih
        const int dir = t / 96, g = t % 96;
        const float* wih = dir ? w_ih_b : w_ih_f;
        const float* bih = dir ? b_ih_b : b_ih_f;
        float acc[NH];
#pragma unroll
        for (int m = 0; m < NH; ++m) acc[m] = 0.0f;
        float ab = bih[g];
        for (int d = 0; d < DH; ++d) {
            float wv = wih[g * DH + d];
            ab = fmaf(wv, b2[d], ab);
#pragma unroll
            for (int m = 0; m < NH; ++m) acc[m] = fmaf(wv, w2[d * NH + m], acc[m]);
        }
#pragma unroll
        for (int m = 0; m < NH; ++m) WC[(dir * 96 + g) * NH + m] = acc[m];
        BC[dir * 96 + g] = ab;
    }
    __syncthreads();

    if (t < 768) {  // gh A-frags (hi/lo, k-permuted) + gx A-frags (rne + bias slots)
        const int dir = t / 384, r = t % 384, tt = r / 64, l = r % 64;
        const int gate = tt * 16 + (l & 15);
        const int q = l >> 4;
        const float* whh = dir ? whh_b : whh_f;
        const float* bhh = dir ? bhh_b : bhh_f;
        unsigned short h8[8], l8[8], g8[8];
#pragma unroll
        for (int e = 0; e < 8; ++e) {
            const int u = kperm(q, e);
            float w = whh[gate * DH + u];
            unsigned ub = __float_as_uint(w);
            h8[e] = (unsigned short)(ub >> 16);
            l8[e] = bf16_rne(w - __uint_as_float(ub & 0xffff0000u));
            float gxv = (e < 4) ? WC[(dir * 96 + gate) * NH + 4 * q + e] : 0.0f;
            g8[e] = bf16_rne(gxv);
        }
        // bias slots: (q=0,e=4) hi, (q=1,e=4) lo; pairs with constant 1.0 in B
        const float bias = BC[dir * 96 + gate] + ((gate < 64) ? bhh[gate] : 0.0f);
        const unsigned bb = __float_as_uint(bias);
        if (q == 0) g8[4] = (unsigned short)(bb >> 16);
        if (q == 1) g8[4] = bf16_rne(bias - __uint_as_float(bb & 0xffff0000u));

        unsigned short* dh = (unsigned short*)(ws + OFF_AHI + dir * 6144u + tt * 1024u + l * 16u);
        unsigned short* dl = (unsigned short*)(ws + OFF_ALO + dir * 6144u + tt * 1024u + l * 16u);
        unsigned short* dg = (unsigned short*)(ws + OFF_AGX + dir * 6144u + tt * 1024u + l * 16u);
#pragma unroll
        for (int e = 0; e < 8; ++e) { dh[e] = h8[e]; dl[e] = l8[e]; dg[e] = g8[e]; }
    }
    {  // decoder A-frags: A[out][k] k-permuted, k = pi(q,e) + 32*kc
        const int kc = t / 512, r = t % 512, tt = r / 64, l = r % 64;
        const int outn = tt * 16 + (l & 15);
        const int q = l >> 4;
        unsigned short* dd = (unsigned short*)(ws + OFF_ADEC + kc * 8192u + tt * 1024u + l * 16u);
#pragma unroll
        for (int e = 0; e < 8; ++e)
            dd[e] = bf16_rne(w_dec[outn * 64 + kperm(q, e) + 32 * kc]);
    }
}

__global__ __launch_bounds__(128, 2) void gru_mfma_kernel(
    const float* __restrict__ x,
    const float* __restrict__ w1, const float* __restrict__ b1,
    const float* __restrict__ bhh_f, const float* __restrict__ bhh_b,
    const unsigned char* __restrict__ ws,
    const float* __restrict__ b_dec,
    float* __restrict__ out)
{
    __shared__ __align__(16) u32x4 lds_comb[2][64][2];  // [wave][lane][hi/lo] 4KB

    const int tid = threadIdx.x;
    const int dir = tid >> 6;   // wave0 = fwd, wave1 = bwd
    const int l   = tid & 63;
    const int n = l & 15;       // batch row (D col / B col)
    const int q = l >> 4;       // k-quad / D row-quad
    const int rowbase = blockIdx.x * 16;
    const float* xr = x + (size_t)(rowbase + n) * SEQB;

    const float4 w1q = *(const float4*)(w1 + 4 * q);  // h1 units 4q..4q+3
    const float4 b1q = *(const float4*)(b1 + 4 * q);

    const float* bhh = dir ? bhh_b : bhh_f;
    const unsigned char* pAhi = ws + OFF_AHI + dir * 6144u + l * 16u;
    const unsigned char* pAlo = ws + OFF_ALO + dir * 6144u + l * 16u;
    const unsigned char* pAgx = ws + OFF_AGX + dir * 6144u + l * 16u;
    s16x8 Ahi[6], Alo[6], Agx[6];
#pragma unroll
    for (int tt = 0; tt < 6; ++tt) {
        Ahi[tt] = *(const s16x8*)(pAhi + tt * 1024);
        Alo[tt] = *(const s16x8*)(pAlo + tt * 1024);
        Agx[tt] = *(const s16x8*)(pAgx + tt * 1024);
    }
#pragma unroll
    for (int tt = 0; tt < 6; ++tt)
        asm volatile("" : "+v"(Ahi[tt]), "+v"(Alo[tt]), "+v"(Agx[tt]));
    // n-gate gh bias (C-init of the gh chain): gates 64+4q+rg (tile4), 80+4q+rg (tile5)
    const float4 bn0f = *(const float4*)(bhh + 64 + 4 * q);
    const float4 bn1f = *(const float4*)(bhh + 80 + 4 * q);
    const f32x4 bhn0 = {bn0f.x, bn0f.y, bn0f.z, bn0f.w};
    const f32x4 bhn1 = {bn1f.x, bn1f.y, bn1f.z, bn1f.w};

    float hL[4] = {0, 0, 0, 0}, hH[4] = {0, 0, 0, 0};
    float pL[4] = {0, 0, 0, 0}, pH[4] = {0, 0, 0, 0};

#pragma unroll 1
    for (int blk = 0; blk < 4; ++blk) {
        const int bb = dir ? 3 - blk : blk;
        const float4 xa = *(const float4*)(xr + bb * 8);
        const float4 xb = *(const float4*)(xr + bb * 8 + 4);
        float xs[8] = {xa.x, xa.y, xa.z, xa.w, xb.x, xb.y, xb.z, xb.w};
        if (dir) {  // wave-uniform branch: reverse within the 8-step chunk
            float r0 = xs[0], r1 = xs[1], r2 = xs[2], r3 = xs[3];
            xs[0] = xs[7]; xs[1] = xs[6]; xs[2] = xs[5]; xs[3] = xs[4];
            xs[4] = r3; xs[5] = r2; xs[6] = r1; xs[7] = r0;
        }

#pragma unroll
        for (int i = 0; i < 8; ++i) {
            // ---- B_h1 frag: h1[row n][4q+e] e<4 (in-lane), e4=1.0 (bias), e5..7=0
            float t0 = fmaf(xs[i], w1q.x, b1q.x); t0 = fmaxf(t0, 0.01f * t0);
            float t1 = fmaf(xs[i], w1q.y, b1q.y); t1 = fmaxf(t1, 0.01f * t1);
            float t2 = fmaf(xs[i], w1q.z, b1q.z); t2 = fmaxf(t2, 0.01f * t2);
            float t3 = fmaf(xs[i], w1q.w, b1q.w); t3 = fmaxf(t3, 0.01f * t3);
            u32x4 ub1;
            ub1.x = pack_hi(__float_as_uint(t1), __float_as_uint(t0));
            ub1.y = pack_hi(__float_as_uint(t3), __float_as_uint(t2));
            ub1.z = 0x00003F80u;  // e4 = 1.0 (bias partner), e5 = 0
            ub1.w = 0u;           // e6, e7 = 0
            const s16x8 Bh1 = __builtin_bit_cast(s16x8, ub1);

            // ---- B_h frags hi/lo from in-lane h state (u-order: L=4q+rg, H=16+4q+rg)
            unsigned uL0 = __float_as_uint(hL[0]), uL1 = __float_as_uint(hL[1]);
            unsigned uL2 = __float_as_uint(hL[2]), uL3 = __float_as_uint(hL[3]);
            unsigned uH0 = __float_as_uint(hH[0]), uH1 = __float_as_uint(hH[1]);
            unsigned uH2 = __float_as_uint(hH[2]), uH3 = __float_as_uint(hH[3]);
            u32x4 phh;
            phh.x = pack_hi(uL1, uL0); phh.y = pack_hi(uL3, uL2);
            phh.z = pack_hi(uH1, uH0); phh.w = pack_hi(uH3, uH2);
            float lL0 = hL[0] - __uint_as_float(uL0 & 0xffff0000u);
            float lL1 = hL[1] - __uint_as_float(uL1 & 0xffff0000u);
            float lL2 = hL[2] - __uint_as_float(uL2 & 0xffff0000u);
            float lL3 = hL[3] - __uint_as_float(uL3 & 0xffff0000u);
            float lH0 = hH[0] - __uint_as_float(uH0 & 0xffff0000u);
            float lH1 = hH[1] - __uint_as_float(uH1 & 0xffff0000u);
            float lH2 = hH[2] - __uint_as_float(uH2 & 0xffff0000u);
            float lH3 = hH[3] - __uint_as_float(uH3 & 0xffff0000u);
            u32x4 phl;
            phl.x = pack_hi(__float_as_uint(lL1), __float_as_uint(lL0));
            phl.y = pack_hi(__float_as_uint(lL3), __float_as_uint(lL2));
            phl.z = pack_hi(__float_as_uint(lH1), __float_as_uint(lH0));
            phl.w = pack_hi(__float_as_uint(lH3), __float_as_uint(lH2));
            const s16x8 Bhhi = __builtin_bit_cast(s16x8, phh);
            const s16x8 Bhlo = __builtin_bit_cast(s16x8, phl);

            const f32x4 z4 = {0.0f, 0.0f, 0.0f, 0.0f};
            // r tiles (gates 0..15 / 16..31): gx+bias then 3-term gh, one chain
            f32x4 a0 = MFMA_B16(Agx[0], Bh1, z4);
            a0 = MFMA_B16(Alo[0], Bhhi, a0); a0 = MFMA_B16(Ahi[0], Bhlo, a0); a0 = MFMA_B16(Ahi[0], Bhhi, a0);
            f32x4 a1 = MFMA_B16(Agx[1], Bh1, z4);
            a1 = MFMA_B16(Alo[1], Bhhi, a1); a1 = MFMA_B16(Ahi[1], Bhlo, a1); a1 = MFMA_B16(Ahi[1], Bhhi, a1);
            // z tiles
            f32x4 a2 = MFMA_B16(Agx[2], Bh1, z4);
            a2 = MFMA_B16(Alo[2], Bhhi, a2); a2 = MFMA_B16(Ahi[2], Bhlo, a2); a2 = MFMA_B16(Ahi[2], Bhhi, a2);
            f32x4 a3 = MFMA_B16(Agx[3], Bh1, z4);
            a3 = MFMA_B16(Alo[3], Bhhi, a3); a3 = MFMA_B16(Ahi[3], Bhlo, a3); a3 = MFMA_B16(Ahi[3], Bhhi, a3);
            // n tiles: gx (with bcn in bias slot) and gh (C-init = bhn) kept separate
            f32x4 x4a = MFMA_B16(Agx[4], Bh1, z4);
            f32x4 x5a = MFMA_B16(Agx[5], Bh1, z4);
            f32x4 g4 = MFMA_B16(Alo[4], Bhhi, bhn0);
            g4 = MFMA_B16(Ahi[4], Bhlo, g4); g4 = MFMA_B16(Ahi[4], Bhhi, g4);
            f32x4 g5 = MFMA_B16(Alo[5], Bhhi, bhn1);
            g5 = MFMA_B16(Ahi[5], Bhlo, g5); g5 = MFMA_B16(Ahi[5], Bhhi, g5);

            // ---- activations + state update (all in-lane, fp32)
#pragma unroll
            for (int rg = 0; rg < 4; ++rg) {
                float rL = __builtin_amdgcn_rcpf(1.0f + __expf(-a0[rg]));
                float zL = __builtin_amdgcn_rcpf(1.0f + __expf(-a2[rg]));
                float tL = fmaf(rL, g4[rg], x4a[rg]);
                float nL = fmaf(-2.0f, __builtin_amdgcn_rcpf(1.0f + __expf(tL + tL)), 1.0f);
                hL[rg] = fmaf(zL, hL[rg] - nL, nL);
                pL[rg] += hL[rg];

                float rH = __builtin_amdgcn_rcpf(1.0f + __expf(-a1[rg]));
                float zH = __builtin_amdgcn_rcpf(1.0f + __expf(-a3[rg]));
                float tH = fmaf(rH, g5[rg], x5a[rg]);
                float nH = fmaf(-2.0f, __builtin_amdgcn_rcpf(1.0f + __expf(tH + tH)), 1.0f);
                hH[rg] = fmaf(zH, hH[rg] - nH, nH);
                pH[rg] += hH[rg];
            }
        }
    }

    // ---- pack this wave's pooled into bf16 hi/lo frags, exchange via LDS ----
    {
#pragma unroll
        for (int rg = 0; rg < 4; ++rg) { pL[rg] *= 0.03125f; pH[rg] *= 0.03125f; }
        unsigned v0, v1, v2, v3;
        u32x4 ph, pl;
        v0 = __float_as_uint(pL[0]); v1 = __float_as_uint(pL[1]);
        v2 = __float_as_uint(pL[2]); v3 = __float_as_uint(pL[3]);
        ph.x = pack_hi(v1, v0); ph.y = pack_hi(v3, v2);
        pl.x = pack_hi(__float_as_uint(pL[1] - __uint_as_float(v1 & 0xffff0000u)),
                       __float_as_uint(pL[0] - __uint_as_float(v0 & 0xffff0000u)));
        pl.y = pack_hi(__float_as_uint(pL[3] - __uint_as_float(v3 & 0xffff0000u)),
                       __float_as_uint(pL[2] - __uint_as_float(v2 & 0xffff0000u)));
        v0 = __float_as_uint(pH[0]); v1 = __float_as_uint(pH[1]);
        v2 = __float_as_uint(pH[2]); v3 = __float_as_uint(pH[3]);
        ph.z = pack_hi(v1, v0); ph.w = pack_hi(v3, v2);
        pl.z = pack_hi(__float_as_uint(pH[1] - __uint_as_float(v1 & 0xffff0000u)),
                       __float_as_uint(pH[0] - __uint_as_float(v0 & 0xffff0000u)));
        pl.w = pack_hi(__float_as_uint(pH[3] - __uint_as_float(v3 & 0xffff0000u)),
                       __float_as_uint(pH[2] - __uint_as_float(v2 & 0xffff0000u)));

        lds_comb[dir][l][0] = ph;
        lds_comb[dir][l][1] = pl;
        __syncthreads();
        const u32x4 oh = lds_comb[dir ^ 1][l][0];
        const u32x4 ol = lds_comb[dir ^ 1][l][1];

        s16x8 BFh, BFl, BBh, BBl;
        if (dir == 0) {
            BFh = __builtin_bit_cast(s16x8, ph); BFl = __builtin_bit_cast(s16x8, pl);
            BBh = __builtin_bit_cast(s16x8, oh); BBl = __builtin_bit_cast(s16x8, ol);
        } else {
            BFh = __builtin_bit_cast(s16x8, oh); BFl = __builtin_bit_cast(s16x8, ol);
            BBh = __builtin_bit_cast(s16x8, ph); BBl = __builtin_bit_cast(s16x8, pl);
        }

        // ---- decoder: this wave handles output tiles tt = dir*4 .. dir*4+3
#pragma unroll
        for (int ti = 0; ti < 4; ++ti) {
            const int tt = dir * 4 + ti;
            const s16x8 A0 = *(const s16x8*)(ws + OFF_ADEC + tt * 1024u + l * 16u);
            const s16x8 A1 = *(const s16x8*)(ws + OFF_ADEC + 8192u + tt * 1024u + l * 16u);
            const float4 bd = *(const float4*)(b_dec + tt * 16 + 4 * q);
            f32x4 acc = {bd.x, bd.y, bd.z, bd.w};
            acc = MFMA_B16(A0, BFl, acc);
            acc = MFMA_B16(A1, BBl, acc);
            acc = MFMA_B16(A0, BFh, acc);
            acc = MFMA_B16(A1, BBh, acc);
            *(float4*)(out + (size_t)(rowbase + n) * 128 + tt * 16 + 4 * q) =
                make_float4(acc[0], acc[1], acc[2], acc[3]);
        }
    }
}

extern "C" void kernel_launch(void* const* d_in, const int* in_sizes, int n_in,
                              void* d_out, int out_size, void* d_ws, size_t ws_size,
                              hipStream_t stream)
{
    const float* x    = (const float*)d_in[0];
    const float* w1   = (const float*)d_in[1];
    const float* b1   = (const float*)d_in[2];
    const float* w2   = (const float*)d_in[3];
    const float* b2   = (const float*)d_in[4];
    const float* wihf = (const float*)d_in[5];
    const float* whhf = (const float*)d_in[6];
    const float* bihf = (const float*)d_in[7];
    const float* bhhf = (const float*)d_in[8];
    const float* wihb = (const float*)d_in[9];
    const float* whhb = (const float*)d_in[10];
    const float* bihb = (const float*)d_in[11];
    const float* bhhb = (const float*)d_in[12];
    const float* wdec = (const float*)d_in[13];
    const float* bdec = (const float*)d_in[14];
    float* out = (float*)d_out;
    unsigned char* ws = (unsigned char*)d_ws;

    const int B = in_sizes[0] / SEQB;  // 32768
    const int grid = B / 16;           // 16 rows per 128-thread (2-wave) block

    hipLaunchKernelGGL(gru_precompute_kernel, dim3(1), dim3(1024), 0, stream,
                       wihf, bihf, wihb, bihb, w2, b2, whhf, whhb, bhhf, bhhb, wdec, ws);
    hipLaunchKernelGGL(gru_mfma_kernel, dim3(grid), dim3(128), 0, stream,
                       x, w1, b1, bhhf, bhhb, ws, bdec, out);
}